// Round 4
// baseline (637.673 us; speedup 1.0000x reference)
//
#include <hip/hip_runtime.h>
#include <stdint.h>

#define BATCH 32
#define SEQ   2048
#define HDIM  1024

typedef short short8 __attribute__((ext_vector_type(8)));
typedef float f32x4 __attribute__((ext_vector_type(4)));

__device__ __forceinline__ unsigned short f2b(float f) {
    unsigned u = __float_as_uint(f);
    u += 0x7FFFu + ((u >> 16) & 1u);   // round-to-nearest-even
    return (unsigned short)(u >> 16);
}
__device__ __forceinline__ float b2f_lo(unsigned u) {
    return __uint_as_float(u << 16);
}
__device__ __forceinline__ float b2f_hi(unsigned u) {
    return __uint_as_float(u & 0xFFFF0000u);
}
__device__ __forceinline__ float fast_tanh(float x) {
    float ex = __expf(2.0f * x);
    return 1.0f - 2.0f / (ex + 1.0f);
}
__device__ __forceinline__ void gl2lds16(const unsigned short* g, unsigned short* l) {
    __builtin_amdgcn_global_load_lds(
        (const __attribute__((address_space(1))) unsigned int*)g,
        (__attribute__((address_space(3))) unsigned int*)l, 16, 0, 0);
}

// ---------------------------------------------------------------------------
// Kernel 1 (grid=1024): fused prep.
//  - grid-stride convert enc fp32 -> enc_bf (268 MB read, 134 MB write)
//  - We row k -> bf16 (RNE)
//  - qb[b][k] = hidden . Wh^T + attn_b[k]
//  - zero scores; blocks 0..31: zero context slots + copy hidden into out
// ---------------------------------------------------------------------------
__global__ __launch_bounds__(256) void prep_kernel(
    const float* __restrict__ hidden, const float* __restrict__ enc,
    const float* __restrict__ attn_w, const float* __restrict__ attn_b,
    unsigned short* __restrict__ we_bf, float* __restrict__ qb,
    float* __restrict__ scores, unsigned short* __restrict__ enc_bf,
    float* __restrict__ out) {
    int k = blockIdx.x;
    int tid = threadIdx.x;

    // enc -> bf16, 32 grid-stride passes (1024*256*8 = 2M elems per pass)
#pragma unroll 4
    for (int it = 0; it < 32; ++it) {
        size_t i = ((size_t)it * 1024 * 256 + (size_t)k * 256 + tid) * 8;
        const float4* s = (const float4*)(enc + i);
        float4 a = s[0], b = s[1];
        short8 o;
        o[0] = (short)f2b(a.x); o[1] = (short)f2b(a.y);
        o[2] = (short)f2b(a.z); o[3] = (short)f2b(a.w);
        o[4] = (short)f2b(b.x); o[5] = (short)f2b(b.y);
        o[6] = (short)f2b(b.z); o[7] = (short)f2b(b.w);
        *(short8*)(enc_bf + i) = o;
    }

    if (tid < 64) scores[(size_t)k * 64 + tid] = 0.0f;

    // output init: context slots zero + hidden copy (blocks 0..31)
    if (k < BATCH) {
        for (int i = tid; i < HDIM; i += 256) {
            out[(size_t)k * 2048 + i] = 0.0f;
            out[(size_t)k * 2048 + 1024 + i] = hidden[(size_t)k * HDIM + i];
        }
    }

    // We row -> bf16
    {
        const float4* src = (const float4*)(attn_w + (size_t)k * 2048 + 1024);
        float4 v = src[tid];
        ushort4 o;
        o.x = f2b(v.x); o.y = f2b(v.y); o.z = f2b(v.z); o.w = f2b(v.w);
        ((ushort4*)(we_bf + (size_t)k * HDIM))[tid] = o;
    }

    // qb[b][k]
    float part[BATCH];
#pragma unroll
    for (int b = 0; b < BATCH; ++b) part[b] = 0.0f;
    const float* wrow = attn_w + (size_t)k * 2048;
    for (int h = tid; h < HDIM; h += 256) {
        float w = wrow[h];
#pragma unroll
        for (int b = 0; b < BATCH; ++b) part[b] += w * hidden[b * HDIM + h];
    }
    __shared__ float red[4][BATCH];
    int lane = tid & 63, wv = tid >> 6;
#pragma unroll
    for (int b = 0; b < BATCH; ++b) {
        float v = part[b];
        v += __shfl_xor(v, 1);  v += __shfl_xor(v, 2);  v += __shfl_xor(v, 4);
        v += __shfl_xor(v, 8);  v += __shfl_xor(v, 16); v += __shfl_xor(v, 32);
        if (lane == 0) red[wv][b] = v;
    }
    __syncthreads();
    if (tid < BATCH) {
        float v = red[0][tid] + red[1][tid] + red[2][tid] + red[3][tid] + attn_b[k];
        qb[(size_t)tid * HDIM + k] = v;
    }
}

// ---------------------------------------------------------------------------
// Kernel 2: score GEMM. 128x128 tile, BK=64, 256 thr = 4 waves 2x2.
// A = enc_bf, B = we_bf, both staged via global_load_lds 16B with XOR chunk
// swizzle (conflict-free reads). XCD swizzle: 8 ntile-blocks of an mtile
// share blockIdx%8 (same XCD, adjacent) -> A served from that XCD's L2.
// Epilogue: scores[b][s] += sum_n v[n]*tanh(qb[b][n]+C[s][n]) via atomicAdd.
// ---------------------------------------------------------------------------
__global__ __launch_bounds__(256) void score_gemm_kernel(
    const unsigned short* __restrict__ enc_bf, const unsigned short* __restrict__ we_bf,
    const float* __restrict__ qb, const float* __restrict__ v_w,
    float* __restrict__ scores) {
    __shared__ __align__(16) unsigned short Als[128 * 64];   // 16 KB
    __shared__ __align__(16) unsigned short Bls[128 * 64];   // 16 KB

    int tid  = threadIdx.x;
    int lane = tid & 63, w = tid >> 6;
    int wm = w & 1, wn = w >> 1;
    int i15 = lane & 15, q = lane >> 4;

    // XCD-aware decode (verified: FETCH 531->174 MB)
    int raw   = blockIdx.x;
    int ntile = (raw >> 3) & 7;
    int mtile = (raw & 7) + 8 * (raw >> 6);
    int b  = mtile >> 4;
    int s0 = (mtile & 15) * 128;

    const unsigned short* Ag = enc_bf + ((size_t)(b * SEQ + s0)) * HDIM;
    const unsigned short* Bg = we_bf + (size_t)ntile * 128 * HDIM;

    // staging: instr (w,j) -> rows (w*4+j)*8 .. +8; lane i -> row +(i>>3),
    // LDS pos i&7, content chunk = pos ^ (row&7)
    int srow   = lane >> 3;
    int schunk = (lane & 7) ^ srow;
    const unsigned short* Ag_l = Ag + (size_t)srow * HDIM + schunk * 8;
    const unsigned short* Bg_l = Bg + (size_t)srow * HDIM + schunk * 8;
    unsigned short* Al_w = Als + (w * 4) * 512;
    unsigned short* Bl_w = Bls + (w * 4) * 512;

    f32x4 acc[4][4];
#pragma unroll
    for (int mt = 0; mt < 4; ++mt)
#pragma unroll
        for (int nt = 0; nt < 4; ++nt) acc[mt][nt] = (f32x4)0.0f;

    const unsigned short* Abase = Als + (wm * 64 + i15) * 64;
    const unsigned short* Bbase = Bls + (wn * 64 + i15) * 64;

    for (int ks = 0; ks < 16; ++ks) {
        if (ks) __syncthreads();
        int k0 = ks * 64;
#pragma unroll
        for (int j = 0; j < 4; ++j) {
            size_t roff = (size_t)((w * 4 + j) * 8) * HDIM + k0;
            gl2lds16(Ag_l + roff, Al_w + j * 512);
            gl2lds16(Bg_l + roff, Bl_w + j * 512);
        }
        __syncthreads();
#pragma unroll
        for (int k2 = 0; k2 < 2; ++k2) {
            int xr = ((k2 * 4 + q) ^ (i15 & 7)) * 8;
            short8 af[4], bf[4];
#pragma unroll
            for (int mt = 0; mt < 4; ++mt)
                af[mt] = *(const short8*)(Abase + mt * 16 * 64 + xr);
#pragma unroll
            for (int nt = 0; nt < 4; ++nt)
                bf[nt] = *(const short8*)(Bbase + nt * 16 * 64 + xr);
#pragma unroll
            for (int mt = 0; mt < 4; ++mt)
#pragma unroll
                for (int nt = 0; nt < 4; ++nt)
                    acc[mt][nt] = __builtin_amdgcn_mfma_f32_16x16x32_bf16(
                        af[mt], bf[nt], acc[mt][nt], 0, 0, 0);
        }
    }

    // epilogue: C layout col=lane&15 (n), row=q*4+reg (m)
    float sc[4][4];
#pragma unroll
    for (int mt = 0; mt < 4; ++mt)
#pragma unroll
        for (int r = 0; r < 4; ++r) sc[mt][r] = 0.0f;

#pragma unroll
    for (int nt = 0; nt < 4; ++nt) {
        int n = ntile * 128 + wn * 64 + nt * 16 + i15;
        float qv = qb[(size_t)b * HDIM + n];
        float vv = v_w[n];
#pragma unroll
        for (int mt = 0; mt < 4; ++mt)
#pragma unroll
            for (int r = 0; r < 4; ++r)
                sc[mt][r] += vv * fast_tanh(acc[mt][nt][r] + qv);
    }
#pragma unroll
    for (int mt = 0; mt < 4; ++mt)
#pragma unroll
        for (int r = 0; r < 4; ++r) {
            float v = sc[mt][r];
            v += __shfl_xor(v, 1); v += __shfl_xor(v, 2);
            v += __shfl_xor(v, 4); v += __shfl_xor(v, 8);
            if (i15 == 0)
                atomicAdd(&scores[(size_t)b * SEQ + s0 + wm * 64 + mt * 16 + q * 4 + r], v);
        }
}

// ---------------------------------------------------------------------------
// Kernel 3: fused softmax + context. grid = 32 b x 16 s-chunks (128 rows).
// Each block recomputes the row max/denominator from scores (8 KB, L2),
// writes its 128 attn weights, then accumulates its s-chunk's weighted
// enc_bf rows into context via atomicAdd. 256 thr = 2 row-groups x 128
// h-threads, 16 B bf16 loads.
// ---------------------------------------------------------------------------
__global__ __launch_bounds__(256) void context_kernel(
    const unsigned short* __restrict__ enc_bf, const float* __restrict__ scores,
    float* out) {
    int id = blockIdx.x;
    int scid = id & 15, b = id >> 4;
    int tid = threadIdx.x;
    int lane = tid & 63, wv = tid >> 6;
    const float* srow = scores + (size_t)b * SEQ;

    __shared__ float redm[4], reds[4];
    __shared__ float wl[128];

    // softmax stats over all 2048 scores (8 per thread)
    float loc[8];
    float m = -1e30f;
#pragma unroll
    for (int i = 0; i < 8; ++i) {
        loc[i] = srow[tid * 8 + i];
        m = fmaxf(m, loc[i]);
    }
#pragma unroll
    for (int d = 1; d < 64; d <<= 1) m = fmaxf(m, __shfl_xor(m, d));
    if (lane == 0) redm[wv] = m;
    __syncthreads();
    m = fmaxf(fmaxf(redm[0], redm[1]), fmaxf(redm[2], redm[3]));
    float sum = 0.0f;
#pragma unroll
    for (int i = 0; i < 8; ++i) sum += __expf(loc[i] - m);
#pragma unroll
    for (int d = 1; d < 64; d <<= 1) sum += __shfl_xor(sum, d);
    if (lane == 0) reds[wv] = sum;
    __syncthreads();
    float inv = 1.0f / (reds[0] + reds[1] + reds[2] + reds[3]);

    // weights for this block's 128 rows; also write to output
    if (tid < 128) {
        float wgt = __expf(srow[scid * 128 + tid] - m) * inv;
        wl[tid] = wgt;
        out[BATCH * SEQ + (size_t)b * SEQ + scid * 128 + tid] = wgt;
    }
    __syncthreads();

    // weighted accumulate: 2 groups x 64 rows, 128 h-threads x 8 h
    int sg = tid >> 7, ht = tid & 127;
    const unsigned short* ebase =
        enc_bf + ((size_t)(b * SEQ + scid * 128 + sg * 64)) * HDIM + ht * 8;
    float a[8];
#pragma unroll
    for (int i = 0; i < 8; ++i) a[i] = 0.0f;
#pragma unroll 4
    for (int s = 0; s < 64; ++s) {
        uint4 u = *(const uint4*)(ebase + (size_t)s * HDIM);
        float wgt = wl[sg * 64 + s];
        a[0] += wgt * b2f_lo(u.x); a[1] += wgt * b2f_hi(u.x);
        a[2] += wgt * b2f_lo(u.y); a[3] += wgt * b2f_hi(u.y);
        a[4] += wgt * b2f_lo(u.z); a[5] += wgt * b2f_hi(u.z);
        a[6] += wgt * b2f_lo(u.w); a[7] += wgt * b2f_hi(u.w);
    }
    float* o = out + (size_t)b * 2048 + ht * 8;
#pragma unroll
    for (int i = 0; i < 8; ++i) atomicAdd(o + i, a[i]);
}

// ---------------------------------------------------------------------------
extern "C" void kernel_launch(void* const* d_in, const int* in_sizes, int n_in,
                              void* d_out, int out_size, void* d_ws, size_t ws_size,
                              hipStream_t stream) {
    const float* hidden = (const float*)d_in[0];
    const float* enc    = (const float*)d_in[1];
    const float* attn_w = (const float*)d_in[2];
    const float* attn_b = (const float*)d_in[3];
    const float* v_w    = (const float*)d_in[4];
    float* out = (float*)d_out;

    char* ws = (char*)d_ws;
    unsigned short* we_bf = (unsigned short*)ws;                     // 2 MB
    float* qb     = (float*)(ws + (size_t)2097152);                  // 128 KB
    float* scores = (float*)(ws + (size_t)2097152 + 131072);         // 256 KB
    unsigned short* enc_bf =
        (unsigned short*)(ws + (size_t)2097152 + 131072 + 262144);   // 134 MB

    prep_kernel<<<1024, 256, 0, stream>>>(hidden, enc, attn_w, attn_b,
                                          we_bf, qb, scores, enc_bf, out);
    score_gemm_kernel<<<4096, 256, 0, stream>>>(enc_bf, we_bf, qb, v_w, scores);
    context_kernel<<<512, 256, 0, stream>>>(enc_bf, scores, out);
}